// Round 1
// baseline (1540.909 us; speedup 1.0000x reference)
//
#include <hip/hip_runtime.h>
#include <hip/hip_bf16.h>
#include <cstdint>

typedef _Float16 f16;
typedef _Float16 f16x4 __attribute__((ext_vector_type(4)));
typedef _Float16 f16x8 __attribute__((ext_vector_type(8)));
typedef float f32x4 __attribute__((ext_vector_type(4)));

#define B_ 4
#define S_ 4096
#define D_ 2048
#define NH 16
#define BW 128

// ---------------------------------------------------------------------------
// cvt: h (fp32 [S,D]) -> hf (f16 [S,D]) and hT (f16 [D,S]) via LDS transpose
// ---------------------------------------------------------------------------
__global__ __launch_bounds__(256) void cvt_kernel(const float* __restrict__ h,
                                                  f16* __restrict__ hf,
                                                  f16* __restrict__ hT) {
    __shared__ f16 tile[64][72];   // +8 pad to break bank alignment
    int s0 = blockIdx.y * 64;
    int d0 = blockIdx.x * 64;
    int tid = threadIdx.x;
    int r  = tid >> 4;            // 0..15
    int c4 = (tid & 15) * 4;      // 0..60
    #pragma unroll
    for (int rr = r; rr < 64; rr += 16) {
        f32x4 v = *(const f32x4*)(h + (size_t)(s0 + rr) * D_ + d0 + c4);
        f16x4 o;
        o[0] = (f16)v[0]; o[1] = (f16)v[1]; o[2] = (f16)v[2]; o[3] = (f16)v[3];
        *(f16x4*)(hf + (size_t)(s0 + rr) * D_ + d0 + c4) = o;
        tile[rr][c4 + 0] = o[0]; tile[rr][c4 + 1] = o[1];
        tile[rr][c4 + 2] = o[2]; tile[rr][c4 + 3] = o[3];
    }
    __syncthreads();
    #pragma unroll
    for (int dd = r; dd < 64; dd += 16) {
        f16x4 o;
        o[0] = tile[c4 + 0][dd]; o[1] = tile[c4 + 1][dd];
        o[2] = tile[c4 + 2][dd]; o[3] = tile[c4 + 3][dd];
        *(f16x4*)(hT + (size_t)(d0 + dd) * S_ + s0 + c4) = o;
    }
}

// ---------------------------------------------------------------------------
// NT GEMM, m97 structure: C[M,N] = alpha * A[M,K] @ B[N,K]^T   (f16 in, fp32 acc)
// 128x128 tile, BK=32, 256 threads = 4 waves (2x2 of 64x64), 16x16x32 MFMA.
// EPI=0: store C.  EPI=1: fused max-over-rows -> atomicMax into hp[n] (ordered uint).
// ---------------------------------------------------------------------------
__device__ __forceinline__ unsigned f2ord(float f) {
    unsigned u = __float_as_uint(f);
    return (u & 0x80000000u) ? ~u : (u | 0x80000000u);
}

template<int EPI>
__global__ __launch_bounds__(256) void gemm_nt(const f16* __restrict__ A,
                                               const f16* __restrict__ Bm,
                                               float* __restrict__ C,
                                               unsigned* __restrict__ hp,
                                               int M, int N, int K, float alpha) {
    __shared__ f16 lA[128 * 32];
    __shared__ f16 lB[128 * 32];
    int tid  = threadIdx.x;
    int m0   = blockIdx.y * 128;
    int n0   = blockIdx.x * 128;
    int wave = tid >> 6;
    int lane = tid & 63;
    int wr   = (wave >> 1) * 64;
    int wc   = (wave & 1) * 64;
    int l15  = lane & 15;
    int quad = lane >> 4;

    // staging: thread tid covers 16B chunk c of tile: row = c*64 + tid/4, col8 = (tid&3)*8
    const f16* aSrc = A + (size_t)(m0 + (tid >> 2)) * K + (tid & 3) * 8;
    const f16* bSrc = Bm + (size_t)(n0 + (tid >> 2)) * K + (tid & 3) * 8;
    size_t rowStep = (size_t)64 * K;

    f32x4 acc[4][4];
    #pragma unroll
    for (int i = 0; i < 4; i++)
        #pragma unroll
        for (int j = 0; j < 4; j++) acc[i][j] = (f32x4)0.0f;

    for (int k0 = 0; k0 < K; k0 += 32) {
        __builtin_amdgcn_global_load_lds(
            (const __attribute__((address_space(1))) void*)(aSrc),
            (__attribute__((address_space(3))) void*)(lA + tid * 8), 16, 0, 0);
        __builtin_amdgcn_global_load_lds(
            (const __attribute__((address_space(1))) void*)(aSrc + rowStep),
            (__attribute__((address_space(3))) void*)(lA + 2048 + tid * 8), 16, 0, 0);
        __builtin_amdgcn_global_load_lds(
            (const __attribute__((address_space(1))) void*)(bSrc),
            (__attribute__((address_space(3))) void*)(lB + tid * 8), 16, 0, 0);
        __builtin_amdgcn_global_load_lds(
            (const __attribute__((address_space(1))) void*)(bSrc + rowStep),
            (__attribute__((address_space(3))) void*)(lB + 2048 + tid * 8), 16, 0, 0);
        __syncthreads();

        f16x8 af[4], bf[4];
        #pragma unroll
        for (int i = 0; i < 4; i++) {
            af[i] = *(const f16x8*)(lA + (wr + i * 16 + l15) * 32 + quad * 8);
            bf[i] = *(const f16x8*)(lB + (wc + i * 16 + l15) * 32 + quad * 8);
        }
        #pragma unroll
        for (int i = 0; i < 4; i++)
            #pragma unroll
            for (int j = 0; j < 4; j++)
                acc[i][j] = __builtin_amdgcn_mfma_f32_16x16x32_f16(af[i], bf[j], acc[i][j], 0, 0, 0);
        __syncthreads();
        aSrc += 32; bSrc += 32;
    }

    if (EPI == 0) {
        #pragma unroll
        for (int i = 0; i < 4; i++) {
            int row = m0 + wr + i * 16 + quad * 4;
            #pragma unroll
            for (int j = 0; j < 4; j++) {
                int col = n0 + wc + j * 16 + l15;
                float* cp = C + (size_t)row * N + col;
                #pragma unroll
                for (int r = 0; r < 4; r++) cp[(size_t)r * N] = alpha * acc[i][j][r];
            }
        }
    } else {
        #pragma unroll
        for (int j = 0; j < 4; j++) {
            int col = n0 + wc + j * 16 + l15;
            float m = acc[0][j][0];
            #pragma unroll
            for (int i = 0; i < 4; i++)
                #pragma unroll
                for (int r = 0; r < 4; r++) m = fmaxf(m, acc[i][j][r]);
            atomicMax(hp + col, f2ord(m));
        }
    }
}

// ---------------------------------------------------------------------------
// Row softmax: scores fp32 [S,S] -> attn f16 [S,S]; one wg (256 thr) per row
// ---------------------------------------------------------------------------
__global__ __launch_bounds__(256) void softmax_kernel(const float* __restrict__ scores,
                                                      f16* __restrict__ attn) {
    int row = blockIdx.x;
    int tid = threadIdx.x;
    const float* src = scores + (size_t)row * S_;
    f32x4 v[4];
    float m = -3.4e38f;
    #pragma unroll
    for (int j = 0; j < 4; j++) {
        v[j] = *(const f32x4*)(src + tid * 4 + j * 1024);
        #pragma unroll
        for (int e = 0; e < 4; e++) m = fmaxf(m, v[j][e]);
    }
    #pragma unroll
    for (int o = 32; o > 0; o >>= 1) m = fmaxf(m, __shfl_xor(m, o, 64));
    __shared__ float sm[4];
    __shared__ float ss[4];
    int wave = tid >> 6, lane = tid & 63;
    if (lane == 0) sm[wave] = m;
    __syncthreads();
    m = fmaxf(fmaxf(sm[0], sm[1]), fmaxf(sm[2], sm[3]));
    float sum = 0.f;
    #pragma unroll
    for (int j = 0; j < 4; j++)
        #pragma unroll
        for (int e = 0; e < 4; e++) { v[j][e] = __expf(v[j][e] - m); sum += v[j][e]; }
    #pragma unroll
    for (int o = 32; o > 0; o >>= 1) sum += __shfl_xor(sum, o, 64);
    if (lane == 0) ss[wave] = sum;
    __syncthreads();
    sum = ss[0] + ss[1] + ss[2] + ss[3];
    float inv = 1.0f / sum;
    f16* dst = attn + (size_t)row * S_;
    #pragma unroll
    for (int j = 0; j < 4; j++) {
        f16x4 o;
        #pragma unroll
        for (int e = 0; e < 4; e++) o[e] = (f16)(v[j][e] * inv);
        *(f16x4*)(dst + tid * 4 + j * 1024) = o;
    }
}

// ---------------------------------------------------------------------------
// Final fused kernel: block-diag gates (fp32) + combine with pooled-h.
// 8 rows per wg; x rows in LDS (64 KB); thread t -> head t/16, j0=(t&15)*8,
// 8 outputs x 8 rows x 2 gates = 128 accumulators (w reused across rows).
// ---------------------------------------------------------------------------
__global__ __launch_bounds__(256, 2) void final_kernel(const float* __restrict__ x,
                                                       const float* __restrict__ w_in,
                                                       const float* __restrict__ w_a,
                                                       const float* __restrict__ a_param,
                                                       const unsigned* __restrict__ hp_u,
                                                       float* __restrict__ out) {
    __shared__ float xs[8 * 2048];   // exactly 64 KB
    int wg = blockIdx.x;             // B_*S_/8 = 2048
    int b  = wg >> 9;                // 512 wgs per batch
    int s0 = (wg & 511) * 8;
    int tid = threadIdx.x;
    const float* xbase = x + ((size_t)b * S_ + s0) * D_;
    {
        int r  = tid >> 5;           // 0..7
        int c0 = (tid & 31) * 4;
        #pragma unroll
        for (int it = 0; it < 16; it++) {
            int c = c0 + it * 128;
            *(f32x4*)(xs + r * 2048 + c) = *(const f32x4*)(xbase + (size_t)r * D_ + c);
        }
    }
    __syncthreads();

    int hd = tid >> 4;               // 0..15
    int j0 = (tid & 15) * 8;
    const float* wi  = w_in + hd * (BW * BW) + j0;
    const float* wa  = w_a  + hd * (BW * BW) + j0;
    const float* xsh = xs + hd * 128;

    float accx[8][8], acca[8][8];    // [jj][row]
    #pragma unroll
    for (int jj = 0; jj < 8; jj++)
        #pragma unroll
        for (int r = 0; r < 8; r++) { accx[jj][r] = 0.f; acca[jj][r] = 0.f; }

    for (int i = 0; i < 128; i += 4) {
        f32x4 xr[8];
        #pragma unroll
        for (int r = 0; r < 8; r++) xr[r] = *(const f32x4*)(xsh + r * 2048 + i);
        #pragma unroll
        for (int k = 0; k < 4; k++) {
            f32x4 wv0 = *(const f32x4*)(wi + (i + k) * 128);
            f32x4 wv1 = *(const f32x4*)(wi + (i + k) * 128 + 4);
            f32x4 wa0 = *(const f32x4*)(wa + (i + k) * 128);
            f32x4 wa1 = *(const f32x4*)(wa + (i + k) * 128 + 4);
            #pragma unroll
            for (int jj = 0; jj < 8; jj++) {
                float wiv = (jj < 4) ? wv0[jj] : wv1[jj - 4];
                float wav = (jj < 4) ? wa0[jj] : wa1[jj - 4];
                #pragma unroll
                for (int r = 0; r < 8; r++) {
                    accx[jj][r] = fmaf(xr[r][k], wiv, accx[jj][r]);
                    acca[jj][r] = fmaf(xr[r][k], wav, acca[jj][r]);
                }
            }
        }
    }

    float n8sp[8], hpv[8];
    #pragma unroll
    for (int jj = 0; jj < 8; jj++) {
        int d = hd * 128 + j0 + jj;
        n8sp[jj] = -8.f * log1pf(__expf(a_param[d]));
        unsigned u = hp_u[b * D_ + d];
        unsigned bits = (u >> 31) ? (u ^ 0x80000000u) : ~u;
        hpv[jj] = __uint_as_float(bits);
    }
    float* obase = out + ((size_t)b * S_ + s0) * D_ + hd * 128 + j0;
    #pragma unroll
    for (int r = 0; r < 8; r++) {
        f32x4 o0, o1;
        #pragma unroll
        for (int jj = 0; jj < 8; jj++) {
            float gx = 1.f / (1.f + __expf(-accx[jj][r]));
            float ga = 1.f / (1.f + __expf(-acca[jj][r]));
            float a  = __expf(n8sp[jj] * ga);
            float ns = sqrtf(fmaxf(1.f - a * a, 0.f));
            float xv = xs[r * 2048 + hd * 128 + j0 + jj];
            float val = a * hpv[jj] + xv * gx * ns;
            if (jj < 4) o0[jj] = val; else o1[jj - 4] = val;
        }
        *(f32x4*)(obase + (size_t)r * D_) = o0;
        *(f32x4*)(obase + (size_t)r * D_ + 4) = o1;
    }
}

// ---------------------------------------------------------------------------
// Workspace layout (needs ~128.03 MiB):
//   [0,16M)    hf   f16 [S,D]
//   [16M,32M)  hT   f16 [D,S]
//   [32M,96M)  scores fp32 [S,S]
//   [96M,128M) attn f16 [S,S]
//   [128M,+32K) hp ordered-uint [B,D]
// ---------------------------------------------------------------------------
extern "C" void kernel_launch(void* const* d_in, const int* in_sizes, int n_in,
                              void* d_out, int out_size, void* d_ws, size_t ws_size,
                              hipStream_t stream) {
    const float* x       = (const float*)d_in[0];
    const float* h       = (const float*)d_in[1];
    const float* w_in    = (const float*)d_in[2];
    const float* w_a     = (const float*)d_in[3];
    const float* a_param = (const float*)d_in[4];
    float* out = (float*)d_out;

    char* ws = (char*)d_ws;
    f16*      hf     = (f16*)ws;                            // 16 MiB
    f16*      hT     = (f16*)(ws + ((size_t)16 << 20));     // 16 MiB
    float*    scores = (float*)(ws + ((size_t)32 << 20));   // 64 MiB
    f16*      attn   = (f16*)(ws + ((size_t)96 << 20));     // 32 MiB
    unsigned* hp     = (unsigned*)(ws + ((size_t)128 << 20)); // 32 KiB

    hipMemsetAsync(hp, 0, (size_t)B_ * D_ * sizeof(unsigned), stream);

    const float scale = 0.08838834764831845f;  // 1/sqrt(128)
    for (int b = 0; b < B_; b++) {
        const f16* hfc = hf;
        const f16* hTc = hT;
        const float* hb = h + (size_t)b * S_ * D_;
        cvt_kernel<<<dim3(D_ / 64, S_ / 64), 256, 0, stream>>>(hb, hf, hT);
        gemm_nt<0><<<dim3(S_ / 128, S_ / 128), 256, 0, stream>>>(
            hfc, hfc, scores, nullptr, S_, S_, D_, scale);
        softmax_kernel<<<dim3(S_), 256, 0, stream>>>(scores, attn);
        gemm_nt<1><<<dim3(D_ / 128, S_ / 128), 256, 0, stream>>>(
            attn, hTc, nullptr, hp + b * D_, S_, D_, S_, 1.0f);
    }
    final_kernel<<<dim3((B_ * S_) / 8), 256, 0, stream>>>(x, w_in, w_a, a_param, hp, out);
}

// Round 2
// 1400.160 us; speedup vs baseline: 1.1005x; 1.1005x over previous
//
#include <hip/hip_runtime.h>
#include <hip/hip_bf16.h>
#include <cstdint>

typedef _Float16 f16;
typedef _Float16 f16x4 __attribute__((ext_vector_type(4)));
typedef _Float16 f16x8 __attribute__((ext_vector_type(8)));
typedef float f32x4 __attribute__((ext_vector_type(4)));

#define B_ 4
#define S_ 4096
#define D_ 2048
#define NH 16
#define BW 128

// ---------------------------------------------------------------------------
// cvt: h (fp32 [S,D]) -> hf (f16 [S,D]) and hT (f16 [D,S]) via LDS transpose
// ---------------------------------------------------------------------------
__global__ __launch_bounds__(256) void cvt_kernel(const float* __restrict__ h,
                                                  f16* __restrict__ hf,
                                                  f16* __restrict__ hT) {
    __shared__ f16 tile[64][72];   // +8 pad to break bank alignment
    int s0 = blockIdx.y * 64;
    int d0 = blockIdx.x * 64;
    int tid = threadIdx.x;
    int r  = tid >> 4;            // 0..15
    int c4 = (tid & 15) * 4;      // 0..60
    #pragma unroll
    for (int rr = r; rr < 64; rr += 16) {
        f32x4 v = *(const f32x4*)(h + (size_t)(s0 + rr) * D_ + d0 + c4);
        f16x4 o;
        o[0] = (f16)v[0]; o[1] = (f16)v[1]; o[2] = (f16)v[2]; o[3] = (f16)v[3];
        *(f16x4*)(hf + (size_t)(s0 + rr) * D_ + d0 + c4) = o;
        tile[rr][c4 + 0] = o[0]; tile[rr][c4 + 1] = o[1];
        tile[rr][c4 + 2] = o[2]; tile[rr][c4 + 3] = o[3];
    }
    __syncthreads();
    #pragma unroll
    for (int dd = r; dd < 64; dd += 16) {
        f16x4 o;
        o[0] = tile[c4 + 0][dd]; o[1] = tile[c4 + 1][dd];
        o[2] = tile[c4 + 2][dd]; o[3] = tile[c4 + 3][dd];
        *(f16x4*)(hT + (size_t)(d0 + dd) * S_ + s0 + c4) = o;
    }
}

// ---------------------------------------------------------------------------
// prep_wT: w fp32 [16,128,128] -> wT f16 chunked [hd][kc][j][32] where
// wT[hd][kc][j][il] = w[hd][kc*32+il][j]  (B-operand layout for NT gemm)
// ---------------------------------------------------------------------------
__global__ __launch_bounds__(256) void prep_wT(const float* __restrict__ w,
                                               f16* __restrict__ wT) {
    int hd = blockIdx.x;
    const float* src = w + hd * 16384;
    f16* dst = wT + hd * 16384;
    int tid = threadIdx.x;
    int j0 = (tid & 31) * 4;
    #pragma unroll
    for (int p = 0; p < 16; p++) {
        int i = (tid >> 5) + p * 8;
        f32x4 v = *(const f32x4*)(src + i * 128 + j0);
        int kc = i >> 5, il = i & 31;
        #pragma unroll
        for (int e = 0; e < 4; e++)
            dst[kc * 4096 + (j0 + e) * 32 + il] = (f16)v[e];
    }
}

// ---------------------------------------------------------------------------
// NT GEMM, m97 structure: C = alpha * A[M,K] @ B[N,K]^T   (f16 in, fp32 acc)
// 128x128 tile, BK=32, 256 threads = 4 waves (2x2 of 64x64), 16x16x32 MFMA.
// EPI=0: store C as f16.  EPI=1: fused max-over-rows -> atomicMax (ordered uint).
// ---------------------------------------------------------------------------
__device__ __forceinline__ unsigned f2ord(float f) {
    unsigned u = __float_as_uint(f);
    return (u & 0x80000000u) ? ~u : (u | 0x80000000u);
}

template<int EPI>
__global__ __launch_bounds__(256) void gemm_nt(const f16* __restrict__ A,
                                               const f16* __restrict__ Bm,
                                               void* __restrict__ C,
                                               unsigned* __restrict__ hp,
                                               int M, int N, int K, float alpha) {
    __shared__ f16 lA[128 * 32];
    __shared__ f16 lB[128 * 32];
    int tid  = threadIdx.x;
    int m0   = blockIdx.y * 128;
    int n0   = blockIdx.x * 128;
    int wave = tid >> 6;
    int lane = tid & 63;
    int wr   = (wave >> 1) * 64;
    int wc   = (wave & 1) * 64;
    int l15  = lane & 15;
    int quad = lane >> 4;

    const f16* aSrc = A + (size_t)(m0 + (tid >> 2)) * K + (tid & 3) * 8;
    const f16* bSrc = Bm + (size_t)(n0 + (tid >> 2)) * K + (tid & 3) * 8;
    size_t rowStep = (size_t)64 * K;

    f32x4 acc[4][4];
    #pragma unroll
    for (int i = 0; i < 4; i++)
        #pragma unroll
        for (int j = 0; j < 4; j++) acc[i][j] = (f32x4)0.0f;

    for (int k0 = 0; k0 < K; k0 += 32) {
        __builtin_amdgcn_global_load_lds(
            (const __attribute__((address_space(1))) void*)(aSrc),
            (__attribute__((address_space(3))) void*)(lA + tid * 8), 16, 0, 0);
        __builtin_amdgcn_global_load_lds(
            (const __attribute__((address_space(1))) void*)(aSrc + rowStep),
            (__attribute__((address_space(3))) void*)(lA + 2048 + tid * 8), 16, 0, 0);
        __builtin_amdgcn_global_load_lds(
            (const __attribute__((address_space(1))) void*)(bSrc),
            (__attribute__((address_space(3))) void*)(lB + tid * 8), 16, 0, 0);
        __builtin_amdgcn_global_load_lds(
            (const __attribute__((address_space(1))) void*)(bSrc + rowStep),
            (__attribute__((address_space(3))) void*)(lB + 2048 + tid * 8), 16, 0, 0);
        __syncthreads();

        f16x8 af[4], bf[4];
        #pragma unroll
        for (int i = 0; i < 4; i++) {
            af[i] = *(const f16x8*)(lA + (wr + i * 16 + l15) * 32 + quad * 8);
            bf[i] = *(const f16x8*)(lB + (wc + i * 16 + l15) * 32 + quad * 8);
        }
        #pragma unroll
        for (int i = 0; i < 4; i++)
            #pragma unroll
            for (int j = 0; j < 4; j++)
                acc[i][j] = __builtin_amdgcn_mfma_f32_16x16x32_f16(af[i], bf[j], acc[i][j], 0, 0, 0);
        __syncthreads();
        aSrc += 32; bSrc += 32;
    }

    if (EPI == 0) {
        f16* Cf = (f16*)C;
        #pragma unroll
        for (int i = 0; i < 4; i++) {
            int row = m0 + wr + i * 16 + quad * 4;
            #pragma unroll
            for (int j = 0; j < 4; j++) {
                int col = n0 + wc + j * 16 + l15;
                f16* cp = Cf + (size_t)row * N + col;
                #pragma unroll
                for (int r = 0; r < 4; r++) cp[(size_t)r * N] = (f16)(alpha * acc[i][j][r]);
            }
        }
    } else {
        #pragma unroll
        for (int j = 0; j < 4; j++) {
            int col = n0 + wc + j * 16 + l15;
            float m = acc[0][j][0];
            #pragma unroll
            for (int i = 0; i < 4; i++)
                #pragma unroll
                for (int r = 0; r < 4; r++) m = fmaxf(m, acc[i][j][r]);
            atomicMax(hp + col, f2ord(m));
        }
    }
}

// ---------------------------------------------------------------------------
// Row softmax: scores f16 [S,S] -> attn f16 [S,S]; one wg (256 thr) per row
// ---------------------------------------------------------------------------
__global__ __launch_bounds__(256) void softmax_kernel(const f16* __restrict__ scores,
                                                      f16* __restrict__ attn) {
    int row = blockIdx.x;
    int tid = threadIdx.x;
    const f16* src = scores + (size_t)row * S_;
    float v[16];
    #pragma unroll
    for (int j = 0; j < 2; j++) {
        f16x8 raw = *(const f16x8*)(src + tid * 8 + j * 2048);
        #pragma unroll
        for (int e = 0; e < 8; e++) v[j * 8 + e] = (float)raw[e];
    }
    float m = -3.4e38f;
    #pragma unroll
    for (int e = 0; e < 16; e++) m = fmaxf(m, v[e]);
    #pragma unroll
    for (int o = 32; o > 0; o >>= 1) m = fmaxf(m, __shfl_xor(m, o, 64));
    __shared__ float sm[4];
    __shared__ float ss[4];
    int wave = tid >> 6, lane = tid & 63;
    if (lane == 0) sm[wave] = m;
    __syncthreads();
    m = fmaxf(fmaxf(sm[0], sm[1]), fmaxf(sm[2], sm[3]));
    float sum = 0.f;
    #pragma unroll
    for (int e = 0; e < 16; e++) { v[e] = __expf(v[e] - m); sum += v[e]; }
    #pragma unroll
    for (int o = 32; o > 0; o >>= 1) sum += __shfl_xor(sum, o, 64);
    if (lane == 0) ss[wave] = sum;
    __syncthreads();
    sum = ss[0] + ss[1] + ss[2] + ss[3];
    float inv = 1.0f / sum;
    f16* dst = attn + (size_t)row * S_;
    #pragma unroll
    for (int j = 0; j < 2; j++) {
        f16x8 o;
        #pragma unroll
        for (int e = 0; e < 8; e++) o[e] = (f16)(v[j * 8 + e] * inv);
        *(f16x8*)(dst + tid * 8 + j * 2048) = o;
    }
}

// ---------------------------------------------------------------------------
// final2: MFMA gate computation + fused epilogue.
// Block: 512 threads = 8 waves; tile M=256 rows x N=128 (one head), K=128.
// LDS: xs chunked [4][256][32] f16 (64KB) + lwi/lwa [4][128][32] (32KB each).
// ---------------------------------------------------------------------------
__global__ __launch_bounds__(512, 1) void final2_kernel(
    const float* __restrict__ x, const f16* __restrict__ wTi,
    const f16* __restrict__ wTa, const float* __restrict__ a_param,
    const unsigned* __restrict__ hp_u, float* __restrict__ out) {
    __shared__ f16 xs[4 * 256 * 32];   // 64 KB
    __shared__ f16 lwi[16384];         // 32 KB
    __shared__ f16 lwa[16384];         // 32 KB
    int tid  = threadIdx.x;
    int hd   = blockIdx.y;
    int row0 = blockIdx.x * 256;       // row in [0, B*S)
    int b    = row0 >> 12;
    int wave = tid >> 6, lane = tid & 63;

    // stage wT (contiguous 32KB blobs) via global_load_lds width-16
    const f16* wsi = wTi + hd * 16384;
    const f16* wsa = wTa + hd * 16384;
    #pragma unroll
    for (int c = 0; c < 4; c++) {
        int off = (wave * 4 + c) * 512 + lane * 8;   // f16 elements
        __builtin_amdgcn_global_load_lds(
            (const __attribute__((address_space(1))) void*)(wsi + off),
            (__attribute__((address_space(3))) void*)(lwi + off), 16, 0, 0);
        __builtin_amdgcn_global_load_lds(
            (const __attribute__((address_space(1))) void*)(wsa + off),
            (__attribute__((address_space(3))) void*)(lwa + off), 16, 0, 0);
    }

    // stage x tile -> f16 chunked [kc][row][32]
    {
        int rr   = tid >> 4;            // 0..31
        int col8 = (tid & 15) * 8;
        int kc = col8 >> 5, cl = col8 & 31;
        const float* xb = x + (size_t)row0 * D_ + hd * 128;
        #pragma unroll
        for (int it = 0; it < 8; it++) {
            int row = it * 32 + rr;
            f32x4 v0 = *(const f32x4*)(xb + (size_t)row * D_ + col8);
            f32x4 v1 = *(const f32x4*)(xb + (size_t)row * D_ + col8 + 4);
            f16x8 o;
            o[0] = (f16)v0[0]; o[1] = (f16)v0[1]; o[2] = (f16)v0[2]; o[3] = (f16)v0[3];
            o[4] = (f16)v1[0]; o[5] = (f16)v1[1]; o[6] = (f16)v1[2]; o[7] = (f16)v1[3];
            *(f16x8*)(xs + kc * 8192 + row * 32 + cl) = o;
        }
    }
    __syncthreads();

    int wr = (wave >> 1) * 64;   // 0,64,128,192
    int wc = (wave & 1) * 64;    // 0,64
    int l15 = lane & 15, quad = lane >> 4;

    f32x4 ai[4][4], aa[4][4];
    #pragma unroll
    for (int i = 0; i < 4; i++)
        #pragma unroll
        for (int j = 0; j < 4; j++) { ai[i][j] = (f32x4)0.0f; aa[i][j] = (f32x4)0.0f; }

    #pragma unroll
    for (int ks = 0; ks < 4; ks++) {
        f16x8 af[4], bi[4], ba[4];
        #pragma unroll
        for (int i = 0; i < 4; i++)
            af[i] = *(const f16x8*)(xs + ks * 8192 + (wr + i * 16 + l15) * 32 + quad * 8);
        #pragma unroll
        for (int j = 0; j < 4; j++) {
            bi[j] = *(const f16x8*)(lwi + ks * 4096 + (wc + j * 16 + l15) * 32 + quad * 8);
            ba[j] = *(const f16x8*)(lwa + ks * 4096 + (wc + j * 16 + l15) * 32 + quad * 8);
        }
        #pragma unroll
        for (int i = 0; i < 4; i++)
            #pragma unroll
            for (int j = 0; j < 4; j++) {
                ai[i][j] = __builtin_amdgcn_mfma_f32_16x16x32_f16(af[i], bi[j], ai[i][j], 0, 0, 0);
                aa[i][j] = __builtin_amdgcn_mfma_f32_16x16x32_f16(af[i], ba[j], aa[i][j], 0, 0, 0);
            }
    }

    // epilogue
    #pragma unroll
    for (int j = 0; j < 4; j++) {
        int n = wc + j * 16 + l15;
        int d = hd * 128 + n;
        float n8sp = -8.f * log1pf(__expf(a_param[d]));
        unsigned u = hp_u[b * D_ + d];
        unsigned bits = (u >> 31) ? (u ^ 0x80000000u) : ~u;
        float hpv = __uint_as_float(bits);
        int xc = (n >> 5) * 8192 + (n & 31);
        #pragma unroll
        for (int i = 0; i < 4; i++) {
            int mbase = wr + i * 16 + quad * 4;
            #pragma unroll
            for (int r = 0; r < 4; r++) {
                int m = mbase + r;
                float gx = 1.f / (1.f + __expf(-ai[i][j][r]));
                float ga = 1.f / (1.f + __expf(-aa[i][j][r]));
                float a  = __expf(n8sp * ga);
                float ns = sqrtf(fmaxf(1.f - a * a, 0.f));
                float xv = (float)xs[xc + m * 32];
                out[(size_t)(row0 + m) * D_ + d] = a * hpv + xv * gx * ns;
            }
        }
    }
}

// ---------------------------------------------------------------------------
// Workspace layout (~97.1 MiB):
//   [0,16M)      hf     f16 [S,D]
//   [16M,32M)    hT     f16 [D,S]
//   [32M,64M)    scores f16 [S,S]
//   [64M,96M)    attn   f16 [S,S]
//   [96M,+32K)   hp     ordered-uint [B,D]
//   [96M+64K,..) wTi, wTa  f16 [16,128,128] each (512 KiB each)
// ---------------------------------------------------------------------------
extern "C" void kernel_launch(void* const* d_in, const int* in_sizes, int n_in,
                              void* d_out, int out_size, void* d_ws, size_t ws_size,
                              hipStream_t stream) {
    const float* x       = (const float*)d_in[0];
    const float* h       = (const float*)d_in[1];
    const float* w_in    = (const float*)d_in[2];
    const float* w_a     = (const float*)d_in[3];
    const float* a_param = (const float*)d_in[4];
    float* out = (float*)d_out;

    char* ws = (char*)d_ws;
    f16*      hf     = (f16*)ws;                              // 16 MiB
    f16*      hT     = (f16*)(ws + ((size_t)16 << 20));       // 16 MiB
    f16*      scores = (f16*)(ws + ((size_t)32 << 20));       // 32 MiB
    f16*      attn   = (f16*)(ws + ((size_t)64 << 20));       // 32 MiB
    unsigned* hp     = (unsigned*)(ws + ((size_t)96 << 20));  // 32 KiB
    f16*      wTi    = (f16*)(ws + ((size_t)96 << 20) + (64 << 10));
    f16*      wTa    = (f16*)(ws + ((size_t)96 << 20) + (64 << 10) + (512 << 10));

    hipMemsetAsync(hp, 0, (size_t)B_ * D_ * sizeof(unsigned), stream);
    prep_wT<<<dim3(16), 256, 0, stream>>>(w_in, wTi);
    prep_wT<<<dim3(16), 256, 0, stream>>>(w_a, wTa);

    const float scale = 0.08838834764831845f;  // 1/sqrt(128)
    for (int b = 0; b < B_; b++) {
        const float* hb = h + (size_t)b * S_ * D_;
        cvt_kernel<<<dim3(D_ / 64, S_ / 64), 256, 0, stream>>>(hb, hf, hT);
        gemm_nt<0><<<dim3(S_ / 128, S_ / 128), 256, 0, stream>>>(
            hf, hf, (void*)scores, nullptr, S_, S_, D_, scale);
        softmax_kernel<<<dim3(S_), 256, 0, stream>>>(scores, attn);
        gemm_nt<1><<<dim3(D_ / 128, S_ / 128), 256, 0, stream>>>(
            attn, hT, nullptr, hp + b * D_, S_, D_, S_, 1.0f);
    }
    final2_kernel<<<dim3((B_ * S_) / 256, NH), 512, 0, stream>>>(
        x, wTi, wTa, a_param, hp, out);
}

// Round 3
// 1254.583 us; speedup vs baseline: 1.2282x; 1.1160x over previous
//
#include <hip/hip_runtime.h>
#include <hip/hip_bf16.h>
#include <cstdint>

typedef _Float16 f16;
typedef _Float16 f16x4 __attribute__((ext_vector_type(4)));
typedef _Float16 f16x8 __attribute__((ext_vector_type(8)));
typedef float f32x4 __attribute__((ext_vector_type(4)));

#define B_ 4
#define S_ 4096
#define D_ 2048
#define NH 16
#define BW 128

// ---------------------------------------------------------------------------
// cvt: h (fp32 [S,D]) -> hf (f16 [S,D]) and hT (f16 [D,S]) via LDS transpose
// ---------------------------------------------------------------------------
__global__ __launch_bounds__(256) void cvt_kernel(const float* __restrict__ h,
                                                  f16* __restrict__ hf,
                                                  f16* __restrict__ hT) {
    __shared__ f16 tile[64][72];
    int s0 = blockIdx.y * 64;
    int d0 = blockIdx.x * 64;
    int tid = threadIdx.x;
    int r  = tid >> 4;
    int c4 = (tid & 15) * 4;
    #pragma unroll
    for (int rr = r; rr < 64; rr += 16) {
        f32x4 v = *(const f32x4*)(h + (size_t)(s0 + rr) * D_ + d0 + c4);
        f16x4 o;
        o[0] = (f16)v[0]; o[1] = (f16)v[1]; o[2] = (f16)v[2]; o[3] = (f16)v[3];
        *(f16x4*)(hf + (size_t)(s0 + rr) * D_ + d0 + c4) = o;
        tile[rr][c4 + 0] = o[0]; tile[rr][c4 + 1] = o[1];
        tile[rr][c4 + 2] = o[2]; tile[rr][c4 + 3] = o[3];
    }
    __syncthreads();
    #pragma unroll
    for (int dd = r; dd < 64; dd += 16) {
        f16x4 o;
        o[0] = tile[c4 + 0][dd]; o[1] = tile[c4 + 1][dd];
        o[2] = tile[c4 + 2][dd]; o[3] = tile[c4 + 3][dd];
        *(f16x4*)(hT + (size_t)(d0 + dd) * S_ + s0 + c4) = o;
    }
}

// ---------------------------------------------------------------------------
// prep_wT: w fp32 [16,128,128] -> wT f16 chunked [hd][kc][j][32]:
// wT[hd][kc][j][il] = w[hd][kc*32+il][j]   (A/B-operand fragment layout)
// ---------------------------------------------------------------------------
__global__ __launch_bounds__(256) void prep_wT(const float* __restrict__ w,
                                               f16* __restrict__ wT) {
    int hd = blockIdx.x;
    const float* src = w + hd * 16384;
    f16* dst = wT + hd * 16384;
    int tid = threadIdx.x;
    int j0 = (tid & 31) * 4;
    #pragma unroll
    for (int p = 0; p < 16; p++) {
        int i = (tid >> 5) + p * 8;
        f32x4 v = *(const f32x4*)(src + i * 128 + j0);
        int kc = i >> 5, il = i & 31;
        #pragma unroll
        for (int e = 0; e < 4; e++)
            dst[kc * 4096 + (j0 + e) * 32 + il] = (f16)v[e];
    }
}

// prep_nsp: n8sp[d] = -8 * softplus(a_param[d])
__global__ __launch_bounds__(256) void prep_nsp(const float* __restrict__ ap,
                                                float* __restrict__ nsp) {
    int d = blockIdx.x * 256 + threadIdx.x;
    nsp[d] = -8.f * log1pf(__expf(ap[d]));
}

__device__ __forceinline__ unsigned f2ord(float f) {
    unsigned u = __float_as_uint(f);
    return (u & 0x80000000u) ? ~u : (u | 0x80000000u);
}

// ---------------------------------------------------------------------------
// gemm_sym: scores = alpha * A A^T, symmetric; only upper-tri 128x128 tiles.
// blockIdx.x = linear triangular index over (bm <= bn).
// Off-diag blocks written twice (normal f16 scalar + transposed f16x4).
// ---------------------------------------------------------------------------
__global__ __launch_bounds__(256) void gemm_sym(const f16* __restrict__ A,
                                                f16* __restrict__ C,
                                                int K, float alpha) {
    __shared__ f16 lA[128 * 32];
    __shared__ f16 lB[128 * 32];
    int idx = blockIdx.x;
    int bn = (int)((sqrtf(8.f * (float)idx + 1.f) - 1.f) * 0.5f);
    while ((bn + 1) * (bn + 2) / 2 <= idx) bn++;
    while (bn * (bn + 1) / 2 > idx) bn--;
    int bm = idx - bn * (bn + 1) / 2;     // bm <= bn
    int m0 = bm * 128, n0 = bn * 128;

    int tid  = threadIdx.x;
    int wave = tid >> 6;
    int lane = tid & 63;
    int wr   = (wave >> 1) * 64;
    int wc   = (wave & 1) * 64;
    int l15  = lane & 15;
    int quad = lane >> 4;

    const f16* aSrc = A + (size_t)(m0 + (tid >> 2)) * K + (tid & 3) * 8;
    const f16* bSrc = A + (size_t)(n0 + (tid >> 2)) * K + (tid & 3) * 8;
    size_t rowStep = (size_t)64 * K;

    f32x4 acc[4][4];
    #pragma unroll
    for (int i = 0; i < 4; i++)
        #pragma unroll
        for (int j = 0; j < 4; j++) acc[i][j] = (f32x4)0.0f;

    for (int k0 = 0; k0 < K; k0 += 32) {
        __builtin_amdgcn_global_load_lds(
            (const __attribute__((address_space(1))) void*)(aSrc),
            (__attribute__((address_space(3))) void*)(lA + tid * 8), 16, 0, 0);
        __builtin_amdgcn_global_load_lds(
            (const __attribute__((address_space(1))) void*)(aSrc + rowStep),
            (__attribute__((address_space(3))) void*)(lA + 2048 + tid * 8), 16, 0, 0);
        __builtin_amdgcn_global_load_lds(
            (const __attribute__((address_space(1))) void*)(bSrc),
            (__attribute__((address_space(3))) void*)(lB + tid * 8), 16, 0, 0);
        __builtin_amdgcn_global_load_lds(
            (const __attribute__((address_space(1))) void*)(bSrc + rowStep),
            (__attribute__((address_space(3))) void*)(lB + 2048 + tid * 8), 16, 0, 0);
        __syncthreads();

        f16x8 af[4], bf[4];
        #pragma unroll
        for (int i = 0; i < 4; i++) {
            af[i] = *(const f16x8*)(lA + (wr + i * 16 + l15) * 32 + quad * 8);
            bf[i] = *(const f16x8*)(lB + (wc + i * 16 + l15) * 32 + quad * 8);
        }
        #pragma unroll
        for (int i = 0; i < 4; i++)
            #pragma unroll
            for (int j = 0; j < 4; j++)
                acc[i][j] = __builtin_amdgcn_mfma_f32_16x16x32_f16(af[i], bf[j], acc[i][j], 0, 0, 0);
        __syncthreads();
        aSrc += 32; bSrc += 32;
    }

    // normal-orientation store: C[m0-tile][n0-tile]
    #pragma unroll
    for (int i = 0; i < 4; i++) {
        int row = m0 + wr + i * 16 + quad * 4;
        #pragma unroll
        for (int j = 0; j < 4; j++) {
            int col = n0 + wc + j * 16 + l15;
            f16* cp = C + (size_t)row * S_ + col;
            #pragma unroll
            for (int r = 0; r < 4; r++) cp[(size_t)r * S_] = (f16)(alpha * acc[i][j][r]);
        }
    }
    if (bm != bn) {
        // transposed store: C[n0-tile][m0-tile], f16x4 along r (consecutive cols)
        #pragma unroll
        for (int i = 0; i < 4; i++) {
            int colb = m0 + wr + i * 16 + quad * 4;
            #pragma unroll
            for (int j = 0; j < 4; j++) {
                int row = n0 + wc + j * 16 + l15;
                f16x4 o;
                #pragma unroll
                for (int r = 0; r < 4; r++) o[r] = (f16)(alpha * acc[i][j][r]);
                *(f16x4*)(C + (size_t)row * S_ + colb) = o;
            }
        }
    }
}

// ---------------------------------------------------------------------------
// gemm_nt EPI=1 (pooled path): max-over-rows -> atomicMax (ordered uint)
// ---------------------------------------------------------------------------
__global__ __launch_bounds__(256) void gemm_nt_max(const f16* __restrict__ A,
                                                   const f16* __restrict__ Bm,
                                                   unsigned* __restrict__ hp,
                                                   int N, int K) {
    __shared__ f16 lA[128 * 32];
    __shared__ f16 lB[128 * 32];
    int tid  = threadIdx.x;
    int m0   = blockIdx.y * 128;
    int n0   = blockIdx.x * 128;
    int wave = tid >> 6;
    int lane = tid & 63;
    int wr   = (wave >> 1) * 64;
    int wc   = (wave & 1) * 64;
    int l15  = lane & 15;
    int quad = lane >> 4;

    const f16* aSrc = A + (size_t)(m0 + (tid >> 2)) * K + (tid & 3) * 8;
    const f16* bSrc = Bm + (size_t)(n0 + (tid >> 2)) * K + (tid & 3) * 8;
    size_t rowStep = (size_t)64 * K;

    f32x4 acc[4][4];
    #pragma unroll
    for (int i = 0; i < 4; i++)
        #pragma unroll
        for (int j = 0; j < 4; j++) acc[i][j] = (f32x4)0.0f;

    for (int k0 = 0; k0 < K; k0 += 32) {
        __builtin_amdgcn_global_load_lds(
            (const __attribute__((address_space(1))) void*)(aSrc),
            (__attribute__((address_space(3))) void*)(lA + tid * 8), 16, 0, 0);
        __builtin_amdgcn_global_load_lds(
            (const __attribute__((address_space(1))) void*)(aSrc + rowStep),
            (__attribute__((address_space(3))) void*)(lA + 2048 + tid * 8), 16, 0, 0);
        __builtin_amdgcn_global_load_lds(
            (const __attribute__((address_space(1))) void*)(bSrc),
            (__attribute__((address_space(3))) void*)(lB + tid * 8), 16, 0, 0);
        __builtin_amdgcn_global_load_lds(
            (const __attribute__((address_space(1))) void*)(bSrc + rowStep),
            (__attribute__((address_space(3))) void*)(lB + 2048 + tid * 8), 16, 0, 0);
        __syncthreads();

        f16x8 af[4], bf[4];
        #pragma unroll
        for (int i = 0; i < 4; i++) {
            af[i] = *(const f16x8*)(lA + (wr + i * 16 + l15) * 32 + quad * 8);
            bf[i] = *(const f16x8*)(lB + (wc + i * 16 + l15) * 32 + quad * 8);
        }
        #pragma unroll
        for (int i = 0; i < 4; i++)
            #pragma unroll
            for (int j = 0; j < 4; j++)
                acc[i][j] = __builtin_amdgcn_mfma_f32_16x16x32_f16(af[i], bf[j], acc[i][j], 0, 0, 0);
        __syncthreads();
        aSrc += 32; bSrc += 32;
    }

    #pragma unroll
    for (int j = 0; j < 4; j++) {
        int col = n0 + wc + j * 16 + l15;
        float m = acc[0][j][0];
        #pragma unroll
        for (int i = 0; i < 4; i++)
            #pragma unroll
            for (int r = 0; r < 4; r++) m = fmaxf(m, acc[i][j][r]);
        atomicMax(hp + col, f2ord(m));
    }
}

// ---------------------------------------------------------------------------
// Row softmax: scores f16 [S,S] -> attn f16 [S,S]; one wg (256 thr) per row
// ---------------------------------------------------------------------------
__global__ __launch_bounds__(256) void softmax_kernel(const f16* __restrict__ scores,
                                                      f16* __restrict__ attn) {
    int row = blockIdx.x;
    int tid = threadIdx.x;
    const f16* src = scores + (size_t)row * S_;
    float v[16];
    #pragma unroll
    for (int j = 0; j < 2; j++) {
        f16x8 raw = *(const f16x8*)(src + tid * 8 + j * 2048);
        #pragma unroll
        for (int e = 0; e < 8; e++) v[j * 8 + e] = (float)raw[e];
    }
    float m = -3.4e38f;
    #pragma unroll
    for (int e = 0; e < 16; e++) m = fmaxf(m, v[e]);
    #pragma unroll
    for (int o = 32; o > 0; o >>= 1) m = fmaxf(m, __shfl_xor(m, o, 64));
    __shared__ float sm[4];
    __shared__ float ss[4];
    int wave = tid >> 6, lane = tid & 63;
    if (lane == 0) sm[wave] = m;
    __syncthreads();
    m = fmaxf(fmaxf(sm[0], sm[1]), fmaxf(sm[2], sm[3]));
    float sum = 0.f;
    #pragma unroll
    for (int e = 0; e < 16; e++) { v[e] = __expf(v[e] - m); sum += v[e]; }
    #pragma unroll
    for (int o = 32; o > 0; o >>= 1) sum += __shfl_xor(sum, o, 64);
    if (lane == 0) ss[wave] = sum;
    __syncthreads();
    sum = ss[0] + ss[1] + ss[2] + ss[3];
    float inv = 1.0f / sum;
    f16* dst = attn + (size_t)row * S_;
    #pragma unroll
    for (int j = 0; j < 2; j++) {
        f16x8 o;
        #pragma unroll
        for (int e = 0; e < 8; e++) o[e] = (f16)(v[j * 8 + e] * inv);
        *(f16x8*)(dst + tid * 8 + j * 2048) = o;
    }
}

// ---------------------------------------------------------------------------
// final3: TRANSPOSED gate GEMM (gate^T = w^T x^T). Zero LDS, zero barriers.
// Block 256 thr = 4 waves; tile = 32 x-rows x 128 gate-cols (one head).
// Wave w: 32 gate-cols [w*32, w*32+32), both gates; acc = 8 f32x4.
// D-layout: gate-col = quad*4+r (4 consecutive per lane!), x-row = l15
// -> epilogue is pure f32x4 loads/stores.
// ---------------------------------------------------------------------------
__global__ __launch_bounds__(256, 4) void final3_kernel(
    const float* __restrict__ x, const f16* __restrict__ wTi,
    const f16* __restrict__ wTa, const float* __restrict__ nsp_arr,
    const unsigned* __restrict__ hp_u, float* __restrict__ out) {
    int tid  = threadIdx.x;
    int hd   = blockIdx.y;
    int row0 = blockIdx.x * 32;
    int b    = row0 >> 12;
    int wave = tid >> 6, lane = tid & 63;
    int l15  = lane & 15, quad = lane >> 4;
    int jbase = wave * 32;

    const f16* wi = wTi + hd * 16384;
    const f16* wa = wTa + hd * 16384;
    const float* xb = x + (size_t)row0 * D_ + hd * 128;

    f32x4 accx[2][2], acca[2][2];
    #pragma unroll
    for (int im = 0; im < 2; im++)
        #pragma unroll
        for (int jn = 0; jn < 2; jn++) { accx[im][jn] = (f32x4)0.0f; acca[im][jn] = (f32x4)0.0f; }

    #pragma unroll
    for (int ks = 0; ks < 4; ks++) {
        f16x8 bf[2];
        #pragma unroll
        for (int jn = 0; jn < 2; jn++) {
            const float* p = xb + (size_t)(jn * 16 + l15) * D_ + ks * 32 + quad * 8;
            f32x4 v0 = *(const f32x4*)p;
            f32x4 v1 = *(const f32x4*)(p + 4);
            f16x8 o;
            o[0] = (f16)v0[0]; o[1] = (f16)v0[1]; o[2] = (f16)v0[2]; o[3] = (f16)v0[3];
            o[4] = (f16)v1[0]; o[5] = (f16)v1[1]; o[6] = (f16)v1[2]; o[7] = (f16)v1[3];
            bf[jn] = o;
        }
        #pragma unroll
        for (int im = 0; im < 2; im++) {
            int joff = (jbase + im * 16 + l15) * 32 + quad * 8;
            f16x8 afx = *(const f16x8*)(wi + ks * 4096 + joff);
            f16x8 afa = *(const f16x8*)(wa + ks * 4096 + joff);
            #pragma unroll
            for (int jn = 0; jn < 2; jn++) {
                accx[im][jn] = __builtin_amdgcn_mfma_f32_16x16x32_f16(afx, bf[jn], accx[im][jn], 0, 0, 0);
                acca[im][jn] = __builtin_amdgcn_mfma_f32_16x16x32_f16(afa, bf[jn], acca[im][jn], 0, 0, 0);
            }
        }
    }

    #pragma unroll
    for (int im = 0; im < 2; im++) {
        int dl = hd * 128 + jbase + im * 16 + quad * 4;
        f32x4 nsp = *(const f32x4*)(nsp_arr + dl);
        uint4 hu = *(const uint4*)(hp_u + b * D_ + dl);
        float hpv[4];
        {
            unsigned uu[4] = {hu.x, hu.y, hu.z, hu.w};
            #pragma unroll
            for (int r = 0; r < 4; r++) {
                unsigned u = uu[r];
                unsigned bits = (u >> 31) ? (u ^ 0x80000000u) : ~u;
                hpv[r] = __uint_as_float(bits);
            }
        }
        #pragma unroll
        for (int jn = 0; jn < 2; jn++) {
            int row = row0 + jn * 16 + l15;
            f32x4 xv = *(const f32x4*)(x + (size_t)row * D_ + dl);
            f32x4 o;
            #pragma unroll
            for (int r = 0; r < 4; r++) {
                float gx = 1.f / (1.f + __expf(-accx[im][jn][r]));
                float ga = 1.f / (1.f + __expf(-acca[im][jn][r]));
                float a  = __expf(nsp[r] * ga);
                float ns = sqrtf(fmaxf(1.f - a * a, 0.f));
                o[r] = a * hpv[r] + xv[r] * gx * ns;
            }
            *(f32x4*)(out + (size_t)row * D_ + dl) = o;
        }
    }
}

// ---------------------------------------------------------------------------
// Workspace (~98.2 MiB):
//   [0,16M)   hf f16 [S,D]      [16M,32M) hT f16 [D,S]
//   [32M,64M) scores f16 [S,S]  [64M,96M) attn f16 [S,S]
//   [96M)     hp u32 [B,D]      [96M+64K) wTi, wTa (512K each), nsp (8K)
// ---------------------------------------------------------------------------
extern "C" void kernel_launch(void* const* d_in, const int* in_sizes, int n_in,
                              void* d_out, int out_size, void* d_ws, size_t ws_size,
                              hipStream_t stream) {
    const float* x       = (const float*)d_in[0];
    const float* h       = (const float*)d_in[1];
    const float* w_in    = (const float*)d_in[2];
    const float* w_a     = (const float*)d_in[3];
    const float* a_param = (const float*)d_in[4];
    float* out = (float*)d_out;

    char* ws = (char*)d_ws;
    f16*      hf     = (f16*)ws;
    f16*      hT     = (f16*)(ws + ((size_t)16 << 20));
    f16*      scores = (f16*)(ws + ((size_t)32 << 20));
    f16*      attn   = (f16*)(ws + ((size_t)64 << 20));
    unsigned* hp     = (unsigned*)(ws + ((size_t)96 << 20));
    f16*      wTi    = (f16*)(ws + ((size_t)96 << 20) + (64 << 10));
    f16*      wTa    = (f16*)(ws + ((size_t)96 << 20) + (64 << 10) + (512 << 10));
    float*    nsp    = (float*)(ws + ((size_t)96 << 20) + (64 << 10) + (1024 << 10));

    hipMemsetAsync(hp, 0, (size_t)B_ * D_ * sizeof(unsigned), stream);
    prep_wT<<<dim3(16), 256, 0, stream>>>(w_in, wTi);
    prep_wT<<<dim3(16), 256, 0, stream>>>(w_a, wTa);
    prep_nsp<<<dim3(8), 256, 0, stream>>>(a_param, nsp);

    const float scale = 0.08838834764831845f;  // 1/sqrt(128)
    for (int b = 0; b < B_; b++) {
        const float* hb = h + (size_t)b * S_ * D_;
        cvt_kernel<<<dim3(D_ / 64, S_ / 64), 256, 0, stream>>>(hb, hf, hT);
        gemm_sym<<<dim3(528), 256, 0, stream>>>(hf, scores, D_, scale);
        softmax_kernel<<<dim3(S_), 256, 0, stream>>>(scores, attn);
        gemm_nt_max<<<dim3(D_ / 128, S_ / 128), 256, 0, stream>>>(
            attn, hT, hp + b * D_, D_, S_);
    }
    final3_kernel<<<dim3((B_ * S_) / 32, NH), 256, 0, stream>>>(
        x, wTi, wTa, nsp, hp, out);
}